// Round 9
// baseline (94.642 us; speedup 1.0000x reference)
//
#include <hip/hip_runtime.h>
#include <hip/hip_bf16.h>
#include <stdint.h>

// Q8_0 dequant linear: y = x @ W^T + bias.  M=N=K=4096.
// INT8 path, m201-exact schedule: per K-tile 4 phases, each phase =
// {ds_reads (same-phase operands) + 1 half-tile stage -> [lgkmcnt(8) if 12
//  reads] -> barrier -> lgkmcnt(0) -> sched_barrier -> setprio MFMA -> barrier},
// ONE vmcnt(6) per tile at phase 4. Stage order: A1(t+1), B0(t+2), B1(t+2),
// A0(t+2). XOR-swizzled LDS (0 conflicts), hoisted imm-offset read bases.

#define M_DIM 4096
#define N_DIM 4096
#define K_DIM 4096
#define NB_SC 128

#define BM 256
#define BN 256
#define BKB 128                  // K-tile bytes (= elements, i8)
#define NT (K_DIM / BKB)         // 32 K-tiles
#define TILE_B (BM * BKB)        // 32 KiB per tile buffer

typedef __attribute__((ext_vector_type(4))) int i32x4;

__device__ __forceinline__ void gload_lds16(const void* gsrc, void* ldsdst) {
  __builtin_amdgcn_global_load_lds(
      (__attribute__((address_space(1))) void*)(uintptr_t)gsrc,
      (__attribute__((address_space(3))) void*)(uint32_t)(uintptr_t)ldsdst,
      16, 0, 0);
}

__device__ __forceinline__ int pack4(int a, int b, int c, int d) {
  return (a & 255) | ((b & 255) << 8) | ((c & 255) << 16) | ((d & 255) << 24);
}

// ---------------- fused prep kernel ----------------

__global__ void prep_kernel(const float* __restrict__ x, const int* __restrict__ q,
                            const float* __restrict__ sc,
                            char* __restrict__ xb, char* __restrict__ wb,
                            float* __restrict__ sxv, float* __restrict__ swv) {
  __shared__ float red[4];
  const int b = blockIdx.x;
  const int t = threadIdx.x;
  if (b < 4096) {
    const float4* row = (const float4*)(x + (size_t)b * K_DIM);
    float4 v[4];
    float m = 0.f;
#pragma unroll
    for (int i = 0; i < 4; ++i) {
      v[i] = row[t * 4 + i];
      m = fmaxf(m, fmaxf(fmaxf(fabsf(v[i].x), fabsf(v[i].y)),
                         fmaxf(fabsf(v[i].z), fabsf(v[i].w))));
    }
#pragma unroll
    for (int off = 32; off >= 1; off >>= 1) m = fmaxf(m, __shfl_xor(m, off, 64));
    if ((t & 63) == 0) red[t >> 6] = m;
    __syncthreads();
    m = fmaxf(fmaxf(red[0], red[1]), fmaxf(red[2], red[3]));
    const float inv = (m > 0.f) ? 127.0f / m : 0.f;
    int4 o;
    o.x = pack4(__float2int_rn(v[0].x * inv), __float2int_rn(v[0].y * inv),
                __float2int_rn(v[0].z * inv), __float2int_rn(v[0].w * inv));
    o.y = pack4(__float2int_rn(v[1].x * inv), __float2int_rn(v[1].y * inv),
                __float2int_rn(v[1].z * inv), __float2int_rn(v[1].w * inv));
    o.z = pack4(__float2int_rn(v[2].x * inv), __float2int_rn(v[2].y * inv),
                __float2int_rn(v[2].z * inv), __float2int_rn(v[2].w * inv));
    o.w = pack4(__float2int_rn(v[3].x * inv), __float2int_rn(v[3].y * inv),
                __float2int_rn(v[3].z * inv), __float2int_rn(v[3].w * inv));
    ((int4*)(xb + (size_t)b * K_DIM))[t] = o;
    if (t == 0) sxv[b] = m / 127.0f;
  } else {
    const int o_row = b - 4096;
    float m = sc[o_row * NB_SC + (t & 127)];
#pragma unroll
    for (int off = 32; off >= 1; off >>= 1) m = fmaxf(m, __shfl_xor(m, off, 64));
    if ((t & 63) == 0) red[t >> 6] = m;
    __syncthreads();
    m = fmaxf(fmaxf(red[0], red[1]), fmaxf(red[2], red[3]));
    const float ratio = sc[o_row * NB_SC + (t >> 1)] / m;   // scales >= 1e-4 > 0
    const int4* qp = (const int4*)(q + (size_t)o_row * K_DIM);
    int4 qv[4];
#pragma unroll
    for (int i = 0; i < 4; ++i) qv[i] = qp[t * 4 + i];
    int4 ov;
    ov.x = pack4(__float2int_rn((float)qv[0].x * ratio), __float2int_rn((float)qv[0].y * ratio),
                 __float2int_rn((float)qv[0].z * ratio), __float2int_rn((float)qv[0].w * ratio));
    ov.y = pack4(__float2int_rn((float)qv[1].x * ratio), __float2int_rn((float)qv[1].y * ratio),
                 __float2int_rn((float)qv[1].z * ratio), __float2int_rn((float)qv[1].w * ratio));
    ov.z = pack4(__float2int_rn((float)qv[2].x * ratio), __float2int_rn((float)qv[2].y * ratio),
                 __float2int_rn((float)qv[2].z * ratio), __float2int_rn((float)qv[2].w * ratio));
    ov.w = pack4(__float2int_rn((float)qv[3].x * ratio), __float2int_rn((float)qv[3].y * ratio),
                 __float2int_rn((float)qv[3].z * ratio), __float2int_rn((float)qv[3].w * ratio));
    ((int4*)(wb + (size_t)o_row * K_DIM))[t] = ov;
    if (t == 0) swv[o_row] = m;
  }
}

// ---------------- 256x256 BK=128 i8 GEMM (m201-exact schedule) ----------------
// LDS tile [256][128] i8, 128B rows = 8 x 16B granules; logical granule g of
// row r at granule g^(r&7). ds_reads = hoisted lane-const base + imm offset.

__device__ __forceinline__ void stage_half(const char* __restrict__ pX,
                                           char* lds, int hr0, int ktb, int w) {
#pragma unroll
  for (int j = 0; j < 2; ++j) {
    gload_lds16(pX + (size_t)(hr0 + j * 8) * K_DIM + ktb,
                lds + (hr0 + w * 16 + j * 8) * BKB);
  }
}

template <int BUF, int Q>
__device__ __forceinline__ void read_aq(const char* pa0, const char* pa1,
                                        i32x4 (&af)[2][2]) {
#pragma unroll
  for (int j = 0; j < 2; ++j) {
    af[j][0] = *(const i32x4*)(pa0 + BUF * TILE_B + (Q * 32 + j * 16) * BKB);
    af[j][1] = *(const i32x4*)(pa1 + BUF * TILE_B + (Q * 32 + j * 16) * BKB);
  }
}

template <int BUF>
__device__ __forceinline__ void read_ball(const char* pb0, const char* pb1,
                                          i32x4 (&bf)[4][2]) {
#pragma unroll
  for (int ni = 0; ni < 4; ++ni) {
    bf[ni][0] = *(const i32x4*)(pb0 + BUF * TILE_B + ni * 16 * BKB);
    bf[ni][1] = *(const i32x4*)(pb1 + BUF * TILE_B + ni * 16 * BKB);
  }
}

__device__ __forceinline__ void mfma_quad(const i32x4 (&af)[2][2], const i32x4 (&bf)[4][2],
                                          i32x4 (&acc)[8][4], int q0) {
  __builtin_amdgcn_s_setprio(1);
#pragma unroll
  for (int q = 0; q < 2; ++q)
#pragma unroll
    for (int ni = 0; ni < 4; ++ni)
#pragma unroll
      for (int kk = 0; kk < 2; ++kk)
        acc[q0 + q][ni] =
            __builtin_amdgcn_mfma_i32_16x16x64_i8(af[q][kk], bf[ni][kk], acc[q0 + q][ni], 0, 0, 0);
  __builtin_amdgcn_s_setprio(0);
}

#define PHASE_SYNC()                                   \
  __builtin_amdgcn_s_barrier();                        \
  asm volatile("s_waitcnt lgkmcnt(0)" ::: "memory");   \
  __builtin_amdgcn_sched_barrier(0)

// MODE: 0 steady; 1 = t==NT-2 (stage A1(t+1) only, vmcnt(0)); 2 = last tile
template <int BUF, int MODE>
__device__ __forceinline__ void ktile(const char* pa0, const char* pa1,
                                      const char* pb0, const char* pb1,
                                      const char* __restrict__ pA,
                                      const char* __restrict__ pB,
                                      char* AsB, char* BsB,
                                      int ktb, int w,
                                      i32x4 (&acc)[8][4]) {
  char* Anw = AsB + (BUF ^ 1) * TILE_B;   // A1(t+1) -> other buffer
  char* Aw  = AsB + BUF * TILE_B;         // A0(t+2) -> current buffer
  char* Bw  = BsB + BUF * TILE_B;         // B(t+2)  -> current buffer

  i32x4 bf[4][2];

  // ph1: read B(t) all (8) + a-q0 (4); stage A1(t+1); 12 reads -> lgkm hint
  {
    i32x4 a0[2][2];
    read_ball<BUF>(pb0, pb1, bf);
    read_aq<BUF, 0>(pa0, pa1, a0);
    if (MODE < 2) stage_half(pA, Anw, 128, ktb + BKB, w);
    asm volatile("s_waitcnt lgkmcnt(8)" ::: "memory");
    PHASE_SYNC();
    mfma_quad(a0, bf, acc, 0);
    __builtin_amdgcn_s_barrier();
  }
  // ph2: read a-q1; stage B0(t+2)
  {
    i32x4 a1[2][2];
    read_aq<BUF, 1>(pa0, pa1, a1);
    if (MODE == 0) stage_half(pB, Bw, 0, ktb + 2 * BKB, w);
    PHASE_SYNC();
    mfma_quad(a1, bf, acc, 2);
    __builtin_amdgcn_s_barrier();
  }
  // ph3: read a-q2; stage B1(t+2)
  {
    i32x4 a2[2][2];
    read_aq<BUF, 2>(pa0, pa1, a2);
    if (MODE == 0) stage_half(pB, Bw, 128, ktb + 2 * BKB, w);
    PHASE_SYNC();
    mfma_quad(a2, bf, acc, 4);
    __builtin_amdgcn_s_barrier();
  }
  // ph4: read a-q3 (before stage in program order); stage A0(t+2);
  // single per-tile counted vmcnt after the MFMA cluster
  {
    i32x4 a3[2][2];
    read_aq<BUF, 3>(pa0, pa1, a3);
    if (MODE == 0) stage_half(pA, Aw, 0, ktb + 2 * BKB, w);
    PHASE_SYNC();
    mfma_quad(a3, bf, acc, 6);
    if (MODE == 0)
      asm volatile("s_waitcnt vmcnt(6)" ::: "memory");  // t+1 landed; 3 halves of t+2 in flight
    else if (MODE == 1)
      asm volatile("s_waitcnt vmcnt(0)" ::: "memory");
    __builtin_amdgcn_s_barrier();
  }
}

__global__ __launch_bounds__(512, 2) void gemm256(const char* __restrict__ A,
                                                  const char* __restrict__ B,
                                                  const float* __restrict__ sxv,
                                                  const float* __restrict__ swv,
                                                  const float* __restrict__ bias,
                                                  float* __restrict__ C) {
  __shared__ char AsB[2 * TILE_B];   // 64 KiB
  __shared__ char BsB[2 * TILE_B];   // 64 KiB

  const int tid = threadIdx.x;
  const int w = tid >> 6;
  const int l = tid & 63;
  const int wm = w >> 2;
  const int wn = w & 3;
  const int frow = l & 15;
  const int fkb = (l >> 4) * 16;

  const int bid = blockIdx.x;
  const int cpx = gridDim.x >> 3;
  const int swz = (bid & 7) * cpx + (bid >> 3);
  const int bm0 = (swz >> 4) * BM;
  const int bn0 = (swz & 15) * BN;

  // hoisted lane-constant LDS read bases (XOR term constant: rows step by 16)
  const int fr7 = frow & 7;
  const int sw0 = (((fkb) >> 4) ^ fr7) << 4;
  const int sw1 = (((fkb + 64) >> 4) ^ fr7) << 4;
  const char* pa0 = (const char*)AsB + (wm * 128 + frow) * BKB + sw0;
  const char* pa1 = (const char*)AsB + (wm * 128 + frow) * BKB + sw1;
  const char* pb0 = (const char*)BsB + (wn * 64 + frow) * BKB + sw0;
  const char* pb1 = (const char*)BsB + (wn * 64 + frow) * BKB + sw1;

  // lane-constant global stage bases (pre-swizzled source granule)
  const int sr = l >> 3;
  const int skp = ((l & 7) ^ sr) << 4;
  const char* pA = A + (size_t)(bm0 + w * 16 + sr) * K_DIM + skp;
  const char* pB = B + (size_t)(bn0 + w * 16 + sr) * K_DIM + skp;

  i32x4 acc[8][4] = {};

  // Prologue: tile0 {B0,B1,A0,A1} -> buf0; tile1 {B0,B1,A0} -> buf1 (A1(1)
  // staged in ph1 of tile 0). vmcnt(6): tile0 fully landed, 3 halves in flight.
  stage_half(pB, BsB, 0, 0, w);
  stage_half(pB, BsB, 128, 0, w);
  stage_half(pA, AsB, 0, 0, w);
  stage_half(pA, AsB, 128, 0, w);
  stage_half(pB, BsB + TILE_B, 0, BKB, w);
  stage_half(pB, BsB + TILE_B, 128, BKB, w);
  stage_half(pA, AsB + TILE_B, 0, BKB, w);
  asm volatile("s_waitcnt vmcnt(6)" ::: "memory");
  __builtin_amdgcn_s_barrier();

  for (int t = 0; t < NT - 2; t += 2) {
    ktile<0, 0>(pa0, pa1, pb0, pb1, pA, pB, AsB, BsB, t * BKB, w, acc);
    ktile<1, 0>(pa0, pa1, pb0, pb1, pA, pB, AsB, BsB, (t + 1) * BKB, w, acc);
  }
  ktile<0, 1>(pa0, pa1, pb0, pb1, pA, pB, AsB, BsB, (NT - 2) * BKB, w, acc);
  ktile<1, 2>(pa0, pa1, pb0, pb1, pA, pB, AsB, BsB, (NT - 1) * BKB, w, acc);

  // Epilogue: y = s_x[m]*s_w[n]*acc + bias[n]; C/D col=l&15, row=(l>>4)*4+r
#pragma unroll
  for (int ni = 0; ni < 4; ++ni) {
    const int n = bn0 + wn * 64 + ni * 16 + (l & 15);
    const float swn = swv[n];
    const float bv = bias[n];
#pragma unroll
    for (int mi = 0; mi < 8; ++mi) {
      const int mbase = bm0 + wm * 128 + mi * 16 + (l >> 4) * 4;
#pragma unroll
      for (int r = 0; r < 4; ++r)
        C[(size_t)(mbase + r) * N_DIM + n] =
            (float)acc[mi][ni][r] * (swn * sxv[mbase + r]) + bv;
    }
  }
}

// ---------------- naive fallback ----------------

__global__ void naive_kernel(const float* __restrict__ x, const int* __restrict__ q,
                             const float* __restrict__ sc, const float* __restrict__ bias,
                             float* __restrict__ out) {
  size_t idx = (size_t)blockIdx.x * blockDim.x + threadIdx.x;
  if (idx >= (size_t)M_DIM * N_DIM) return;
  int n = (int)(idx & (N_DIM - 1));
  size_t m = idx >> 12;
  float acc = 0.f;
  for (int k = 0; k < K_DIM; k += 32) {
    float s = sc[n * NB_SC + (k >> 5)];
    float part = 0.f;
    for (int j = 0; j < 32; ++j)
      part += x[m * K_DIM + k + j] * (float)q[(size_t)n * K_DIM + k + j];
    acc += part * s;
  }
  out[idx] = acc + bias[n];
}

// ---------------- launch ----------------

extern "C" void kernel_launch(void* const* d_in, const int* in_sizes, int n_in,
                              void* d_out, int out_size, void* d_ws, size_t ws_size,
                              hipStream_t stream) {
  const float* x    = (const float*)d_in[0];
  const int*   q    = (const int*)d_in[1];
  const float* sc   = (const float*)d_in[2];
  const float* bias = (const float*)d_in[3];
  float* out = (float*)d_out;

  const size_t elems = (size_t)M_DIM * K_DIM;
  const size_t need  = 2 * elems + 2 * 4096 * sizeof(float);

  if (ws_size >= need) {
    char* xb = (char*)d_ws;
    char* wb = xb + elems;
    float* sxv = (float*)(wb + elems);
    float* swv = sxv + 4096;
    hipLaunchKernelGGL(prep_kernel, dim3(8192), dim3(256), 0, stream,
                       x, q, sc, xb, wb, sxv, swv);
    hipLaunchKernelGGL(gemm256, dim3((M_DIM / BM) * (N_DIM / BN)), dim3(512), 0, stream,
                       xb, wb, sxv, swv, bias, out);
  } else {
    hipLaunchKernelGGL(naive_kernel, dim3((M_DIM * N_DIM) / 256), dim3(256), 0, stream,
                       x, q, sc, bias, out);
  }
}

// Round 10
// 92.655 us; speedup vs baseline: 1.0214x; 1.0214x over previous
//
#include <hip/hip_runtime.h>
#include <hip/hip_bf16.h>
#include <stdint.h>

// Q8_0 dequant linear: y = x @ W^T + bias.  M=N=K=4096.
// INT8 path, FREE-RUNNING schedule: A double-buffer + B triple-buffer
// (160 KiB LDS) makes every staged region disjoint from every region read
// in the same tile -> NO intra-tile barriers. Each wave issues its stages,
// then 24 ds_reads + 64 MFMAs with compiler-counted lgkm; waves drift so
// one wave's LDS reads overlap another's MFMAs. One lgkm(0)+vmcnt(4)+barrier
// per tile. XOR-swizzled LDS (0 conflicts), hoisted imm-offset read bases.

#define M_DIM 4096
#define N_DIM 4096
#define K_DIM 4096
#define NB_SC 128

#define BM 256
#define BN 256
#define BKB 128                  // K-tile bytes (= elements, i8)
#define NT (K_DIM / BKB)         // 32 K-tiles
#define TILE_B (BM * BKB)        // 32 KiB per tile buffer

typedef __attribute__((ext_vector_type(4))) int i32x4;

__device__ __forceinline__ void gload_lds16(const void* gsrc, void* ldsdst) {
  __builtin_amdgcn_global_load_lds(
      (__attribute__((address_space(1))) void*)(uintptr_t)gsrc,
      (__attribute__((address_space(3))) void*)(uint32_t)(uintptr_t)ldsdst,
      16, 0, 0);
}

__device__ __forceinline__ int pack4(int a, int b, int c, int d) {
  return (a & 255) | ((b & 255) << 8) | ((c & 255) << 16) | ((d & 255) << 24);
}

// ---------------- fused prep kernel ----------------

__global__ void prep_kernel(const float* __restrict__ x, const int* __restrict__ q,
                            const float* __restrict__ sc,
                            char* __restrict__ xb, char* __restrict__ wb,
                            float* __restrict__ sxv, float* __restrict__ swv) {
  __shared__ float red[4];
  const int b = blockIdx.x;
  const int t = threadIdx.x;
  if (b < 4096) {
    const float4* row = (const float4*)(x + (size_t)b * K_DIM);
    float4 v[4];
    float m = 0.f;
#pragma unroll
    for (int i = 0; i < 4; ++i) {
      v[i] = row[t * 4 + i];
      m = fmaxf(m, fmaxf(fmaxf(fabsf(v[i].x), fabsf(v[i].y)),
                         fmaxf(fabsf(v[i].z), fabsf(v[i].w))));
    }
#pragma unroll
    for (int off = 32; off >= 1; off >>= 1) m = fmaxf(m, __shfl_xor(m, off, 64));
    if ((t & 63) == 0) red[t >> 6] = m;
    __syncthreads();
    m = fmaxf(fmaxf(red[0], red[1]), fmaxf(red[2], red[3]));
    const float inv = (m > 0.f) ? 127.0f / m : 0.f;
    int4 o;
    o.x = pack4(__float2int_rn(v[0].x * inv), __float2int_rn(v[0].y * inv),
                __float2int_rn(v[0].z * inv), __float2int_rn(v[0].w * inv));
    o.y = pack4(__float2int_rn(v[1].x * inv), __float2int_rn(v[1].y * inv),
                __float2int_rn(v[1].z * inv), __float2int_rn(v[1].w * inv));
    o.z = pack4(__float2int_rn(v[2].x * inv), __float2int_rn(v[2].y * inv),
                __float2int_rn(v[2].z * inv), __float2int_rn(v[2].w * inv));
    o.w = pack4(__float2int_rn(v[3].x * inv), __float2int_rn(v[3].y * inv),
                __float2int_rn(v[3].z * inv), __float2int_rn(v[3].w * inv));
    ((int4*)(xb + (size_t)b * K_DIM))[t] = o;
    if (t == 0) sxv[b] = m / 127.0f;
  } else {
    const int o_row = b - 4096;
    float m = sc[o_row * NB_SC + (t & 127)];
#pragma unroll
    for (int off = 32; off >= 1; off >>= 1) m = fmaxf(m, __shfl_xor(m, off, 64));
    if ((t & 63) == 0) red[t >> 6] = m;
    __syncthreads();
    m = fmaxf(fmaxf(red[0], red[1]), fmaxf(red[2], red[3]));
    const float ratio = sc[o_row * NB_SC + (t >> 1)] / m;   // scales >= 1e-4 > 0
    const int4* qp = (const int4*)(q + (size_t)o_row * K_DIM);
    int4 qv[4];
#pragma unroll
    for (int i = 0; i < 4; ++i) qv[i] = qp[t * 4 + i];
    int4 ov;
    ov.x = pack4(__float2int_rn((float)qv[0].x * ratio), __float2int_rn((float)qv[0].y * ratio),
                 __float2int_rn((float)qv[0].z * ratio), __float2int_rn((float)qv[0].w * ratio));
    ov.y = pack4(__float2int_rn((float)qv[1].x * ratio), __float2int_rn((float)qv[1].y * ratio),
                 __float2int_rn((float)qv[1].z * ratio), __float2int_rn((float)qv[1].w * ratio));
    ov.z = pack4(__float2int_rn((float)qv[2].x * ratio), __float2int_rn((float)qv[2].y * ratio),
                 __float2int_rn((float)qv[2].z * ratio), __float2int_rn((float)qv[2].w * ratio));
    ov.w = pack4(__float2int_rn((float)qv[3].x * ratio), __float2int_rn((float)qv[3].y * ratio),
                 __float2int_rn((float)qv[3].z * ratio), __float2int_rn((float)qv[3].w * ratio));
    ((int4*)(wb + (size_t)o_row * K_DIM))[t] = ov;
    if (t == 0) swv[o_row] = m;
  }
}

// ---------------- 256x256 BK=128 i8 GEMM, free-running ----------------
// LDS tile [256][128] i8, 128B rows = 8 x 16B granules; logical granule g of
// row r at granule g^(r&7). ds_reads = hoisted lane-const base + imm offset.

__device__ __forceinline__ void stage_half(const char* __restrict__ pX,
                                           char* lds, int hr0, int ktb, int w) {
#pragma unroll
  for (int j = 0; j < 2; ++j) {
    gload_lds16(pX + (size_t)(hr0 + j * 8) * K_DIM + ktb,
                lds + (hr0 + w * 16 + j * 8) * BKB);
  }
}

template <int BUF, int Q>
__device__ __forceinline__ void read_aq(const char* pa0, const char* pa1,
                                        i32x4 (&af)[2][2]) {
#pragma unroll
  for (int j = 0; j < 2; ++j) {
    af[j][0] = *(const i32x4*)(pa0 + BUF * TILE_B + (Q * 32 + j * 16) * BKB);
    af[j][1] = *(const i32x4*)(pa1 + BUF * TILE_B + (Q * 32 + j * 16) * BKB);
  }
}

template <int BUF>
__device__ __forceinline__ void read_ball(const char* pb0, const char* pb1,
                                          i32x4 (&bf)[4][2]) {
#pragma unroll
  for (int ni = 0; ni < 4; ++ni) {
    bf[ni][0] = *(const i32x4*)(pb0 + BUF * TILE_B + ni * 16 * BKB);
    bf[ni][1] = *(const i32x4*)(pb1 + BUF * TILE_B + ni * 16 * BKB);
  }
}

__device__ __forceinline__ void mfma_quad(const i32x4 (&af)[2][2], const i32x4 (&bf)[4][2],
                                          i32x4 (&acc)[8][4], int q0) {
  __builtin_amdgcn_s_setprio(1);
#pragma unroll
  for (int q = 0; q < 2; ++q)
#pragma unroll
    for (int ni = 0; ni < 4; ++ni)
#pragma unroll
      for (int kk = 0; kk < 2; ++kk)
        acc[q0 + q][ni] =
            __builtin_amdgcn_mfma_i32_16x16x64_i8(af[q][kk], bf[ni][kk], acc[q0 + q][ni], 0, 0, 0);
  __builtin_amdgcn_s_setprio(0);
}

// AB = t&1 (A read buffer), BB = t%3 (B read buffer).
// MODE: 0 steady; 1 = t==NT-2 (stage A(t+1) only, vmcnt(0)); 2 = last tile.
// Reads: A[AB], B[BB].  Writes: A[AB^1] (=A(t+1)), B[(BB+2)%3] (=B(t+2)).
// Disjoint -> no intra-tile barriers needed.
template <int AB, int BB, int MODE>
__device__ __forceinline__ void ktile(const char* pa0, const char* pa1,
                                      const char* pb0, const char* pb1,
                                      const char* __restrict__ pA,
                                      const char* __restrict__ pB,
                                      char* AsB, char* BsB,
                                      int ktb, int w,
                                      i32x4 (&acc)[8][4]) {
  char* An = AsB + (AB ^ 1) * TILE_B;
  char* Bw = BsB + ((BB + 2) % 3) * TILE_B;

  // issue all stages up front: they stream into LDS while we compute
  if (MODE < 2) {
    stage_half(pA, An, 0, ktb + BKB, w);
    stage_half(pA, An, 128, ktb + BKB, w);
  }
  if (MODE == 0) {
    stage_half(pB, Bw, 0, ktb + 2 * BKB, w);
    stage_half(pB, Bw, 128, ktb + 2 * BKB, w);
  }

  // reads + MFMAs, compiler-scheduled (counted lgkm keeps reads in flight)
  i32x4 bf[4][2];
  i32x4 a0[2][2], a1[2][2], a2[2][2], a3[2][2];
  read_ball<BB>(pb0, pb1, bf);
  read_aq<AB, 0>(pa0, pa1, a0);
  mfma_quad(a0, bf, acc, 0);
  read_aq<AB, 1>(pa0, pa1, a1);
  mfma_quad(a1, bf, acc, 2);
  read_aq<AB, 2>(pa0, pa1, a2);
  mfma_quad(a2, bf, acc, 4);
  read_aq<AB, 3>(pa0, pa1, a3);
  mfma_quad(a3, bf, acc, 6);

  // tile boundary: own reads done, A(t+1)+B(t+1) landed, then converge
  if (MODE < 2) {
    asm volatile("s_waitcnt lgkmcnt(0)" ::: "memory");
    if (MODE == 0)
      asm volatile("s_waitcnt vmcnt(4)" ::: "memory");  // leaves B(t+2) in flight
    else
      asm volatile("s_waitcnt vmcnt(0)" ::: "memory");
    __builtin_amdgcn_s_barrier();
    __builtin_amdgcn_sched_barrier(0);
  }
}

__global__ __launch_bounds__(512, 2) void gemm256(const char* __restrict__ A,
                                                  const char* __restrict__ B,
                                                  const float* __restrict__ sxv,
                                                  const float* __restrict__ swv,
                                                  const float* __restrict__ bias,
                                                  float* __restrict__ C) {
  __shared__ char AsB[2 * TILE_B];   // 64 KiB (A double buffer)
  __shared__ char BsB[3 * TILE_B];   // 96 KiB (B triple buffer)

  const int tid = threadIdx.x;
  const int w = tid >> 6;
  const int l = tid & 63;
  const int wm = w >> 2;
  const int wn = w & 3;
  const int frow = l & 15;
  const int fkb = (l >> 4) * 16;

  const int bid = blockIdx.x;
  const int cpx = gridDim.x >> 3;
  const int swz = (bid & 7) * cpx + (bid >> 3);
  const int bm0 = (swz >> 4) * BM;
  const int bn0 = (swz & 15) * BN;

  // hoisted lane-constant LDS read bases (XOR term constant: rows step by 16)
  const int fr7 = frow & 7;
  const int sw0 = (((fkb) >> 4) ^ fr7) << 4;
  const int sw1 = (((fkb + 64) >> 4) ^ fr7) << 4;
  const char* pa0 = (const char*)AsB + (wm * 128 + frow) * BKB + sw0;
  const char* pa1 = (const char*)AsB + (wm * 128 + frow) * BKB + sw1;
  const char* pb0 = (const char*)BsB + (wn * 64 + frow) * BKB + sw0;
  const char* pb1 = (const char*)BsB + (wn * 64 + frow) * BKB + sw1;

  // lane-constant global stage bases (pre-swizzled source granule)
  const int sr = l >> 3;
  const int skp = ((l & 7) ^ sr) << 4;
  const char* pA = A + (size_t)(bm0 + w * 16 + sr) * K_DIM + skp;
  const char* pB = B + (size_t)(bn0 + w * 16 + sr) * K_DIM + skp;

  i32x4 acc[8][4] = {};

  // Prologue: A(0)->Abuf0, B(0)->Bbuf0 (8 loads), B(1)->Bbuf1 (4 loads).
  // vmcnt(4): A(0),B(0) landed; B(1) in flight (steady-state invariant).
  stage_half(pA, AsB, 0, 0, w);
  stage_half(pA, AsB, 128, 0, w);
  stage_half(pB, BsB, 0, 0, w);
  stage_half(pB, BsB, 128, 0, w);
  stage_half(pB, BsB + TILE_B, 0, BKB, w);
  stage_half(pB, BsB + TILE_B, 128, BKB, w);
  asm volatile("s_waitcnt vmcnt(4)" ::: "memory");
  __builtin_amdgcn_s_barrier();

  // 6-unrolled main loop (lcm(2,3)): 30 tiles, then 2 peeled
  for (int t = 0; t < NT - 2; t += 6) {
    ktile<0, 0, 0>(pa0, pa1, pb0, pb1, pA, pB, AsB, BsB, (t + 0) * BKB, w, acc);
    ktile<1, 1, 0>(pa0, pa1, pb0, pb1, pA, pB, AsB, BsB, (t + 1) * BKB, w, acc);
    ktile<0, 2, 0>(pa0, pa1, pb0, pb1, pA, pB, AsB, BsB, (t + 2) * BKB, w, acc);
    ktile<1, 0, 0>(pa0, pa1, pb0, pb1, pA, pB, AsB, BsB, (t + 3) * BKB, w, acc);
    ktile<0, 1, 0>(pa0, pa1, pb0, pb1, pA, pB, AsB, BsB, (t + 4) * BKB, w, acc);
    ktile<1, 2, 0>(pa0, pa1, pb0, pb1, pA, pB, AsB, BsB, (t + 5) * BKB, w, acc);
  }
  ktile<0, 0, 1>(pa0, pa1, pb0, pb1, pA, pB, AsB, BsB, (NT - 2) * BKB, w, acc);
  ktile<1, 1, 2>(pa0, pa1, pb0, pb1, pA, pB, AsB, BsB, (NT - 1) * BKB, w, acc);

  // Epilogue: y = s_x[m]*s_w[n]*acc + bias[n]; C/D col=l&15, row=(l>>4)*4+r
#pragma unroll
  for (int ni = 0; ni < 4; ++ni) {
    const int n = bn0 + wn * 64 + ni * 16 + (l & 15);
    const float swn = swv[n];
    const float bv = bias[n];
#pragma unroll
    for (int mi = 0; mi < 8; ++mi) {
      const int mbase = bm0 + wm * 128 + mi * 16 + (l >> 4) * 4;
#pragma unroll
      for (int r = 0; r < 4; ++r)
        C[(size_t)(mbase + r) * N_DIM + n] =
            (float)acc[mi][ni][r] * (swn * sxv[mbase + r]) + bv;
    }
  }
}

// ---------------- naive fallback ----------------

__global__ void naive_kernel(const float* __restrict__ x, const int* __restrict__ q,
                             const float* __restrict__ sc, const float* __restrict__ bias,
                             float* __restrict__ out) {
  size_t idx = (size_t)blockIdx.x * blockDim.x + threadIdx.x;
  if (idx >= (size_t)M_DIM * N_DIM) return;
  int n = (int)(idx & (N_DIM - 1));
  size_t m = idx >> 12;
  float acc = 0.f;
  for (int k = 0; k < K_DIM; k += 32) {
    float s = sc[n * NB_SC + (k >> 5)];
    float part = 0.f;
    for (int j = 0; j < 32; ++j)
      part += x[m * K_DIM + k + j] * (float)q[(size_t)n * K_DIM + k + j];
    acc += part * s;
  }
  out[idx] = acc + bias[n];
}

// ---------------- launch ----------------

extern "C" void kernel_launch(void* const* d_in, const int* in_sizes, int n_in,
                              void* d_out, int out_size, void* d_ws, size_t ws_size,
                              hipStream_t stream) {
  const float* x    = (const float*)d_in[0];
  const int*   q    = (const int*)d_in[1];
  const float* sc   = (const float*)d_in[2];
  const float* bias = (const float*)d_in[3];
  float* out = (float*)d_out;

  const size_t elems = (size_t)M_DIM * K_DIM;
  const size_t need  = 2 * elems + 2 * 4096 * sizeof(float);

  if (ws_size >= need) {
    char* xb = (char*)d_ws;
    char* wb = xb + elems;
    float* sxv = (float*)(wb + elems);
    float* swv = sxv + 4096;
    hipLaunchKernelGGL(prep_kernel, dim3(8192), dim3(256), 0, stream,
                       x, q, sc, xb, wb, sxv, swv);
    hipLaunchKernelGGL(gemm256, dim3((M_DIM / BM) * (N_DIM / BN)), dim3(512), 0, stream,
                       xb, wb, sxv, swv, bias, out);
  } else {
    hipLaunchKernelGGL(naive_kernel, dim3((M_DIM * N_DIM) / 256), dim3(256), 0, stream,
                       x, q, sc, bias, out);
  }
}